// Round 1
// baseline (949.865 us; speedup 1.0000x reference)
//
#include <hip/hip_runtime.h>
#include <math.h>

// ws float layout (needs ~16.8 MB)
#define WS_F1S   0u           // scale * f1_normalized, row-major [8192][128]
#define WS_F2N   (1u<<20)     // f2_normalized, row-major [8192][128]
#define WS_AT1   (2u<<20)     // f1s transposed per group: [g][k][r] (g=1024,k=128,r=8)
#define WS_AT2   (3u<<20)     // f2n transposed per group
#define WS_PART  (4u<<20)     // 2048 per-(pass,group) loss partials

__device__ __forceinline__ void lse_merge(float& m, float& s, float m2, float s2) {
  float M = fmaxf(m, m2);
  if (M == -INFINITY) return;            // both empty: keep (-inf, 0)
  s = s * __expf(m - M) + s2 * __expf(m2 - M);
  m = M;
}

__global__ __launch_bounds__(64) void norm_kernel(
    const float* __restrict__ f1, const float* __restrict__ f2,
    const float* __restrict__ scale_p, float* __restrict__ ws) {
  const int i = blockIdx.x;      // row 0..8191
  const int t = threadIdx.x;     // 0..63
  const float scale = scale_p[0];
  float2 a = ((const float2*)(f1 + (size_t)i * 128))[t];
  float2 b = ((const float2*)(f2 + (size_t)i * 128))[t];
  float ss1 = a.x * a.x + a.y * a.y;
  float ss2 = b.x * b.x + b.y * b.y;
  #pragma unroll
  for (int d = 1; d < 64; d <<= 1) {
    ss1 += __shfl_xor(ss1, d);
    ss2 += __shfl_xor(ss2, d);
  }
  const float inv1 = scale / sqrtf(ss1);
  const float inv2 = 1.0f / sqrtf(ss2);
  const float2 o1 = make_float2(a.x * inv1, a.y * inv1);
  const float2 o2 = make_float2(b.x * inv2, b.y * inv2);
  ((float2*)(ws + WS_F1S + (size_t)i * 128))[t] = o1;
  ((float2*)(ws + WS_F2N + (size_t)i * 128))[t] = o2;
  const int g = i >> 3, r = i & 7;
  const int k0 = t * 2;
  ws[WS_AT1 + (size_t)g * 1024 + (size_t)k0 * 8 + r]       = o1.x;
  ws[WS_AT1 + (size_t)g * 1024 + (size_t)(k0 + 1) * 8 + r] = o1.y;
  ws[WS_AT2 + (size_t)g * 1024 + (size_t)k0 * 8 + r]       = o2.x;
  ws[WS_AT2 + (size_t)g * 1024 + (size_t)(k0 + 1) * 8 + r] = o2.y;
}

// One workgroup = one (pass, group): 8 rows x 8192 cols of S (or S^T).
// Thread t owns column tile*256 + t; 8-lane groups own 8-column blocks.
__global__ __launch_bounds__(256) void main_kernel(
    const float* __restrict__ ws, float* __restrict__ partials) {
  const int w = blockIdx.x;
  const int pass = w >> 10;
  const int g = w & 1023;
  const int t = threadIdx.x;

  const float* __restrict__ At = ws + (pass ? WS_AT2 : WS_AT1);
  const float* __restrict__ B  = ws + (pass ? WS_F1S : WS_F2N);
  const float* __restrict__ Ag = At + (size_t)g * 1024;   // [k][r], wave-uniform

  float m_row[8], s_row[8], sum_row[8], sum_bl[8];
  #pragma unroll
  for (int r = 0; r < 8; ++r) {
    m_row[r] = -INFINITY; s_row[r] = 0.f; sum_row[r] = 0.f; sum_bl[r] = 0.f;
  }
  float m_grp = -INFINITY, s_grp = 0.f, sum_B = 0.f;

  __shared__ float sh_diag_lse[8];
  __shared__ float sh_diag_psum[8];
  __shared__ float sh_Bgg;
  __shared__ float sh_red[4][35];

  const bool lane0 = ((t & 7) == 0);

  for (int tile = 0; tile < 32; ++tile) {
    const int c = (tile << 8) + t;          // this thread's column
    float acc[8] = {0.f,0.f,0.f,0.f,0.f,0.f,0.f,0.f};
    const float4* __restrict__ Brow = (const float4*)(B + (size_t)c * 128);
    #pragma unroll 4
    for (int k4 = 0; k4 < 32; ++k4) {
      const float4 b = Brow[k4];
      const float* __restrict__ a = Ag + (k4 << 5);  // 4 k-slices of 8 rows
      #pragma unroll
      for (int r = 0; r < 8; ++r) acc[r] = fmaf(a[r],      b.x, acc[r]);
      #pragma unroll
      for (int r = 0; r < 8; ++r) acc[r] = fmaf(a[8 + r],  b.y, acc[r]);
      #pragma unroll
      for (int r = 0; r < 8; ++r) acc[r] = fmaf(a[16 + r], b.z, acc[r]);
      #pragma unroll
      for (int r = 0; r < 8; ++r) acc[r] = fmaf(a[24 + r], b.w, acc[r]);
    }

    // per-row stats over this thread's 8-column block (8-lane group reduce)
    float mblk[8], sblk[8];
    #pragma unroll
    for (int r = 0; r < 8; ++r) {
      const float x = acc[r];
      sum_row[r] += x;
      float m = x;
      m = fmaxf(m, __shfl_xor(m, 1));
      m = fmaxf(m, __shfl_xor(m, 2));
      m = fmaxf(m, __shfl_xor(m, 4));
      float e = __expf(x - m);
      e += __shfl_xor(e, 1);
      e += __shfl_xor(e, 2);
      e += __shfl_xor(e, 4);
      mblk[r] = m; sblk[r] = e;   // group-uniform
    }
    // 8x8 block LSE (merge rows)
    float MB = mblk[0];
    #pragma unroll
    for (int r = 1; r < 8; ++r) MB = fmaxf(MB, mblk[r]);
    float SB = 0.f;
    #pragma unroll
    for (int r = 0; r < 8; ++r) SB += sblk[r] * __expf(mblk[r] - MB);

    if (lane0) {
      #pragma unroll
      for (int r = 0; r < 8; ++r) {
        sum_bl[r] += mblk[r] + __logf(sblk[r]);        // sum of block-row LSEs
        lse_merge(m_row[r], s_row[r], mblk[r], sblk[r]);
      }
      sum_B += MB + __logf(SB);                        // sum of block LSEs
      lse_merge(m_grp, s_grp, MB, SB);                 // group LSE
    }
    if ((c >> 3) == g) {                               // diagonal block
      #pragma unroll
      for (int r = 0; r < 8; ++r) {
        float p = acc[r];
        p += __shfl_xor(p, 1);
        p += __shfl_xor(p, 2);
        p += __shfl_xor(p, 4);
        if (lane0) {
          sh_diag_psum[r] = p;
          sh_diag_lse[r]  = mblk[r] + __logf(sblk[r]);
        }
      }
      if (lane0) sh_Bgg = MB + __logf(SB);
    }
  }

  // intra-wave butterfly reductions
  #pragma unroll
  for (int r = 0; r < 8; ++r) {
    #pragma unroll
    for (int d = 1; d < 64; d <<= 1) {
      lse_merge(m_row[r], s_row[r], __shfl_xor(m_row[r], d), __shfl_xor(s_row[r], d));
      sum_row[r] += __shfl_xor(sum_row[r], d);
      sum_bl[r]  += __shfl_xor(sum_bl[r], d);
    }
  }
  #pragma unroll
  for (int d = 1; d < 64; d <<= 1) {
    lse_merge(m_grp, s_grp, __shfl_xor(m_grp, d), __shfl_xor(s_grp, d));
    sum_B += __shfl_xor(sum_B, d);
  }
  const int wave = t >> 6;
  if ((t & 63) == 0) {
    float* o = sh_red[wave];
    #pragma unroll
    for (int r = 0; r < 8; ++r) {
      o[r] = m_row[r]; o[8 + r] = s_row[r]; o[16 + r] = sum_row[r]; o[24 + r] = sum_bl[r];
    }
    o[32] = m_grp; o[33] = s_grp; o[34] = sum_B;
  }
  __syncthreads();

  if (t == 0) {
    float M[8], S[8], RS[8], BL[8];
    float mg = -INFINITY, sg = 0.f, sB = 0.f;
    #pragma unroll
    for (int r = 0; r < 8; ++r) { M[r] = -INFINITY; S[r] = 0.f; RS[r] = 0.f; BL[r] = 0.f; }
    for (int wv = 0; wv < 4; ++wv) {
      const float* o = sh_red[wv];
      #pragma unroll
      for (int r = 0; r < 8; ++r) {
        lse_merge(M[r], S[r], o[r], o[8 + r]);
        RS[r] += o[16 + r];
        BL[r] += o[24 + r];
      }
      lse_merge(mg, sg, o[32], o[33]);
      sB += o[34];
    }
    const float eps = 0.1f;
    const float grp_lse = mg + __logf(sg);
    float grp_sum = 0.f, diag_sum = 0.f;
    #pragma unroll
    for (int r = 0; r < 8; ++r) { grp_sum += RS[r]; diag_sum += sh_diag_psum[r]; }
    const float logK = __logf(8184.0f);   // log(GN - N)
    const float inv_gn = 1.0f / 8192.0f;
    float part = 0.f;
    #pragma unroll
    for (int r = 0; r < 8; ++r) {
      const float row_lse = M[r] + __logf(S[r]);
      // part_slice
      part += ((1.f - eps) * (row_lse - sh_diag_psum[r])
             + (eps * inv_gn) * (row_lse - RS[r])) * inv_gn;
      // whole_slice
      const float a = sh_diag_lse[r];
      const float Mx = fmaxf(a, logK);
      const float pos_lse = Mx + __logf(__expf(a - Mx) + __expf(logK - Mx));
      part += ((1.f - eps) * (row_lse - pos_lse)
             + (eps / 1024.f) * (1024.f * row_lse - BL[r])) * inv_gn;
    }
    // part_block
    part += ((1.f - eps) * (grp_lse - diag_sum * (1.f / 64.f))
           + eps * (grp_lse - grp_sum * (1.f / 65536.f))) * (1.f / 1024.f);
    // whole_block
    part += ((1.f - eps) * (grp_lse - sh_Bgg)
           + (eps / 1024.f) * (1024.f * grp_lse - sB)) * (1.f / 1024.f);
    partials[w] = part;
  }
}

__global__ __launch_bounds__(256) void reduce_kernel(
    const float* __restrict__ partials, float* __restrict__ out) {
  __shared__ float sh[256];
  const int t = threadIdx.x;
  float s = 0.f;
  #pragma unroll
  for (int i = 0; i < 8; ++i) s += partials[i * 256 + t];
  sh[t] = s;
  __syncthreads();
  for (int ofs = 128; ofs > 0; ofs >>= 1) {
    if (t < ofs) sh[t] += sh[t + ofs];
    __syncthreads();
  }
  if (t == 0) out[0] = sh[0] * 0.125f;   // (sum_l1 + sum_l2) / 8
}

extern "C" void kernel_launch(void* const* d_in, const int* in_sizes, int n_in,
                              void* d_out, int out_size, void* d_ws, size_t ws_size,
                              hipStream_t stream) {
  const float* f1 = (const float*)d_in[0];
  const float* f2 = (const float*)d_in[1];
  const float* sc = (const float*)d_in[2];
  float* ws = (float*)d_ws;
  float* out = (float*)d_out;

  hipLaunchKernelGGL(norm_kernel, dim3(8192), dim3(64), 0, stream, f1, f2, sc, ws);
  hipLaunchKernelGGL(main_kernel, dim3(2048), dim3(256), 0, stream, ws, ws + WS_PART);
  hipLaunchKernelGGL(reduce_kernel, dim3(1), dim3(256), 0, stream, ws + WS_PART, out);
}

// Round 3
// 170.611 us; speedup vs baseline: 5.5674x; 5.5674x over previous
//
#include <hip/hip_runtime.h>
#include <math.h>

typedef __attribute__((ext_vector_type(8))) short bf16x8;
typedef __attribute__((ext_vector_type(4))) float f32x4;
typedef unsigned short ushort_t;

#define GN 8192
#define NGRP 1024
#define DDIM 128

// float-array offsets within wf (wf = ws + 4MB; bf16 A1/A2 live in first 4MB)
#define ROWST 0                          // [2][8192][4 chunks][3: esum,raw,sbl]
#define GRPB  (ROWST + 2*GN*4*3)         // [2][1024][4 chunks]  (sum of log 8x8-block sums)
#define DPSUM (GRPB + 2*NGRP*4)          // [2][8192]  raw diag-block row sums
#define DT    (DPSUM + 2*GN)             // [2][8192]  diag-block row sumexp (rel C)
#define DU8   (DT + 2*GN)                // [2][1024]  diag 8x8 block sumexp (rel C)
#define PART  (DU8 + 2*NGRP)             // [64] loss partials

__device__ __forceinline__ ushort_t f2bf(float x) {
  unsigned u = __float_as_uint(x);
  unsigned r = (u + 0x7fffu + ((u >> 16) & 1u)) >> 16;
  return (ushort_t)r;
}

__global__ __launch_bounds__(64) void norm_kernel(
    const float* __restrict__ f1, const float* __restrict__ f2,
    const float* __restrict__ scp, ushort_t* __restrict__ A1,
    ushort_t* __restrict__ A2) {
  const int i = blockIdx.x;      // row
  const int t = threadIdx.x;     // 0..63
  const float scale = scp[0];
  float2 a = ((const float2*)(f1 + (size_t)i * DDIM))[t];
  float2 b = ((const float2*)(f2 + (size_t)i * DDIM))[t];
  float ss1 = a.x * a.x + a.y * a.y;
  float ss2 = b.x * b.x + b.y * b.y;
  #pragma unroll
  for (int d = 1; d < 64; d <<= 1) {
    ss1 += __shfl_xor(ss1, d);
    ss2 += __shfl_xor(ss2, d);
  }
  const float inv1 = scale / sqrtf(ss1);
  const float inv2 = 1.0f / sqrtf(ss2);
  ushort2 o1, o2;
  o1.x = f2bf(a.x * inv1); o1.y = f2bf(a.y * inv1);
  o2.x = f2bf(b.x * inv2); o2.y = f2bf(b.y * inv2);
  ((ushort2*)(A1 + (size_t)i * DDIM))[t] = o1;
  ((ushort2*)(A2 + (size_t)i * DDIM))[t] = o2;
}

// grid 1024: idx = pass<<9 | rowblk<<2 | chunk.
// Block: 64 rows (8 groups) x 2048 cols. 4 waves partition col-tiles (16 cols each).
__global__ __launch_bounds__(256) void gemm_stats(
    const ushort_t* __restrict__ wsu, const float* __restrict__ scp,
    float* __restrict__ wf) {
  const int idx = blockIdx.x;
  const int pass = idx >> 9;
  const int rowblk = (idx >> 2) & 127;
  const int chunk = idx & 3;
  const int t = threadIdx.x;
  const int w = t >> 6;
  const int l = t & 63;
  const int li = l & 15;
  const int q = l >> 4;
  const float C = scp[0];

  const ushort_t* A = pass ? (wsu + (size_t)GN * DDIM) : wsu;
  const ushort_t* B = pass ? wsu : (wsu + (size_t)GN * DDIM);
  const int row0 = rowblk * 64;

  // A fragments: 4 row-subtiles x 4 k-substeps, held in registers
  bf16x8 af[4][4];
  #pragma unroll
  for (int s = 0; s < 4; ++s) {
    #pragma unroll
    for (int ks = 0; ks < 4; ++ks) {
      af[s][ks] = *(const bf16x8*)(const void*)(A + (size_t)(row0 + 16 * s + li) * DDIM + ks * 32 + q * 8);
    }
  }

  float esum[4][4], sraw[4][4], sbl[4][4], sB[4];
  #pragma unroll
  for (int s = 0; s < 4; ++s) {
    sB[s] = 0.f;
    #pragma unroll
    for (int r = 0; r < 4; ++r) { esum[s][r] = 0.f; sraw[s][r] = 0.f; sbl[s][r] = 0.f; }
  }

  const ushort_t* Bp = B + ((size_t)((chunk * 128 + w) * 16) + li) * DDIM + q * 8;
  const int idiag = rowblk - chunk * 32;   // i at which this block/wave hits diag tiles

  bf16x8 bcur[4], bnxt[4];
  #pragma unroll
  for (int ks = 0; ks < 4; ++ks) bnxt[ks] = *(const bf16x8*)(const void*)(Bp + ks * 32);

  #pragma unroll 1
  for (int i = 0; i < 32; ++i) {
    #pragma unroll
    for (int ks = 0; ks < 4; ++ks) bcur[ks] = bnxt[ks];
    if (i < 31) {
      const ushort_t* Bn = Bp + (size_t)(i + 1) * 64 * DDIM;
      #pragma unroll
      for (int ks = 0; ks < 4; ++ks) bnxt[ks] = *(const bf16x8*)(const void*)(Bn + ks * 32);
    }

    f32x4 zv = {0.f, 0.f, 0.f, 0.f};
    f32x4 acc[4];
    #pragma unroll
    for (int s = 0; s < 4; ++s) acc[s] = zv;
    #pragma unroll
    for (int ks = 0; ks < 4; ++ks) {
      #pragma unroll
      for (int s = 0; s < 4; ++s) {
        acc[s] = __builtin_amdgcn_mfma_f32_16x16x32_bf16(af[s][ks], bcur[ks], acc[s], 0, 0, 0);
      }
    }

    #pragma unroll
    for (int s = 0; s < 4; ++s) {
      float tt[4];
      #pragma unroll
      for (int r = 0; r < 4; ++r) {
        float x = acc[s][r];
        sraw[s][r] += x;
        float e = __expf(x - C);
        esum[s][r] += e;
        tt[r] = e;
      }
      #pragma unroll
      for (int r = 0; r < 4; ++r) {
        tt[r] += __shfl_xor(tt[r], 1);
        tt[r] += __shfl_xor(tt[r], 2);
        tt[r] += __shfl_xor(tt[r], 4);
      }
      #pragma unroll
      for (int r = 0; r < 4; ++r) sbl[s][r] += __logf(tt[r]);
      float u = tt[0] + tt[1] + tt[2] + tt[3];
      u += __shfl_xor(u, 16);
      sB[s] += __logf(u);

      if (i == idiag && s == w) {           // this wave's diagonal tile
        float tr[4];
        #pragma unroll
        for (int r = 0; r < 4; ++r) {
          float x = acc[s][r];
          x += __shfl_xor(x, 1);
          x += __shfl_xor(x, 2);
          x += __shfl_xor(x, 4);
          tr[r] = x;
        }
        if (((q >> 1) == ((l >> 3) & 1)) && ((l & 7) == 0)) {
          #pragma unroll
          for (int r = 0; r < 4; ++r) {
            wf[DPSUM + (size_t)pass * GN + row0 + 16 * w + q * 4 + r] = tr[r];
            wf[DT    + (size_t)pass * GN + row0 + 16 * w + q * 4 + r] = tt[r];
          }
        }
        if (l == 0)  wf[DU8 + (size_t)pass * NGRP + rowblk * 8 + 2 * w]     = u;
        if (l == 40) wf[DU8 + (size_t)pass * NGRP + rowblk * 8 + 2 * w + 1] = u;
      }
    }
  }

  // wave-level reduce across the 16 col-lanes (and q-pairs for sB)
  #pragma unroll
  for (int s = 0; s < 4; ++s) {
    #pragma unroll
    for (int r = 0; r < 4; ++r) {
      #pragma unroll
      for (int d = 1; d < 16; d <<= 1) {
        esum[s][r] += __shfl_xor(esum[s][r], d);
        sraw[s][r] += __shfl_xor(sraw[s][r], d);
        sbl[s][r]  += __shfl_xor(sbl[s][r], d);
      }
      sbl[s][r] *= 0.125f;      // 8 lanes per col-block held identical logs
    }
    #pragma unroll
    for (int d = 1; d < 32; d <<= 1) sB[s] += __shfl_xor(sB[s], d);
    sB[s] *= 0.0625f;           // 16 redundant lanes per (group, block)
  }

  __shared__ float redE[4][64], redR[4][64], redL[4][64], redB[4][8];
  if (li == 0) {
    #pragma unroll
    for (int s = 0; s < 4; ++s) {
      #pragma unroll
      for (int r = 0; r < 4; ++r) {
        const int rl = 16 * s + q * 4 + r;
        redE[w][rl] = esum[s][r];
        redR[w][rl] = sraw[s][r];
        redL[w][rl] = sbl[s][r];
      }
    }
    if (q == 0) {
      for (int s = 0; s < 4; ++s) redB[w][2 * s] = sB[s];
    }
    if (q == 2) {
      for (int s = 0; s < 4; ++s) redB[w][2 * s + 1] = sB[s];
    }
  }
  __syncthreads();

  if (t < 64) {
    const float E = redE[0][t] + redE[1][t] + redE[2][t] + redE[3][t];
    const float R = redR[0][t] + redR[1][t] + redR[2][t] + redR[3][t];
    const float L = redL[0][t] + redL[1][t] + redL[2][t] + redL[3][t];
    const size_t o = ROWST + (((size_t)pass * GN + row0 + t) * 4 + chunk) * 3;
    wf[o + 0] = E; wf[o + 1] = R; wf[o + 2] = L;
  }
  if (t < 8) {
    const float s4 = redB[0][t] + redB[1][t] + redB[2][t] + redB[3][t];
    wf[GRPB + ((size_t)pass * NGRP + rowblk * 8 + t) * 4 + chunk] = s4;
  }
}

__global__ __launch_bounds__(256) void loss_kernel(
    const float* __restrict__ wf, const float* __restrict__ scp,
    float* __restrict__ partials) {
  const int b = blockIdx.x;          // 0..63
  const int pass = b >> 5;
  const int rbase = (b & 31) * 256;
  const int t = threadIdx.x;
  const int row = rbase + t;
  const float C = scp[0];
  const float eps = 0.1f;

  const size_t ro = ROWST + (((size_t)pass * GN + row) * 4) * 3;
  float E = 0.f, R = 0.f, L = 0.f;
  #pragma unroll
  for (int ch = 0; ch < 4; ++ch) {
    E += wf[ro + 3 * ch + 0];
    R += wf[ro + 3 * ch + 1];
    L += wf[ro + 3 * ch + 2];
  }
  const float P  = wf[DPSUM + (size_t)pass * GN + row];
  const float Td = wf[DT    + (size_t)pass * GN + row];
  const float logE = __logf(E);
  const float row_lse = C + logE;

  // part_slice
  float acc = ((1.f - eps) * (row_lse - P) + (eps / 8192.f) * (row_lse - R)) * (1.f / 8192.f);
  // whole_slice
  const float dl = C + __logf(Td);
  const float l8 = 9.0099363f;       // log(8192 - 8)
  const float mx = fmaxf(dl, l8);
  const float pos_lse = mx + __logf(__expf(dl - mx) + __expf(l8 - mx));
  acc += ((1.f - eps) * (row_lse - pos_lse) + (eps / 1024.f) * (1024.f * logE - L)) * (1.f / 8192.f);

  __shared__ float shE[256], shR[256], shP[256];
  shE[t] = E; shR[t] = R; shP[t] = P;
  __syncthreads();
  if (t < 32) {
    float Eg = 0.f, Rg = 0.f, Pg = 0.f;
    #pragma unroll
    for (int j = 0; j < 8; ++j) { Eg += shE[t * 8 + j]; Rg += shR[t * 8 + j]; Pg += shP[t * 8 + j]; }
    const int g = (rbase >> 3) + t;
    float SB = 0.f;
    #pragma unroll
    for (int ch = 0; ch < 4; ++ch) SB += wf[GRPB + ((size_t)pass * NGRP + g) * 4 + ch];
    const float U = wf[DU8 + (size_t)pass * NGRP + g];
    const float logEg = __logf(Eg);
    const float grp_lse = C + logEg;
    // part_block
    acc += ((1.f - eps) * (grp_lse - Pg * (1.f / 64.f)) + eps * (grp_lse - Rg * (1.f / 65536.f))) * (1.f / 1024.f);
    // whole_block
    const float dbl = C + __logf(U);
    acc += ((1.f - eps) * (grp_lse - dbl) + (eps / 1024.f) * (1024.f * logEg - SB)) * (1.f / 1024.f);
  }

  #pragma unroll
  for (int d = 1; d < 64; d <<= 1) acc += __shfl_xor(acc, d);
  __shared__ float sr[4];
  if ((t & 63) == 0) sr[t >> 6] = acc;
  __syncthreads();
  if (t == 0) partials[b] = sr[0] + sr[1] + sr[2] + sr[3];
}

__global__ __launch_bounds__(64) void final_kernel(
    const float* __restrict__ partials, float* __restrict__ out) {
  const int t = threadIdx.x;
  float v = partials[t];
  #pragma unroll
  for (int d = 1; d < 64; d <<= 1) v += __shfl_xor(v, d);
  if (t == 0) out[0] = 0.125f * v;
}

extern "C" void kernel_launch(void* const* d_in, const int* in_sizes, int n_in,
                              void* d_out, int out_size, void* d_ws, size_t ws_size,
                              hipStream_t stream) {
  const float* f1 = (const float*)d_in[0];
  const float* f2 = (const float*)d_in[1];
  const float* sc = (const float*)d_in[2];
  ushort_t* wsu = (ushort_t*)d_ws;
  float* wf = (float*)((char*)d_ws + (size_t)2 * GN * DDIM * sizeof(ushort_t));
  float* out = (float*)d_out;

  hipLaunchKernelGGL(norm_kernel, dim3(GN), dim3(64), 0, stream,
                     f1, f2, sc, wsu, wsu + (size_t)GN * DDIM);
  hipLaunchKernelGGL(gemm_stats, dim3(1024), dim3(256), 0, stream, wsu, sc, wf);
  hipLaunchKernelGGL(loss_kernel, dim3(64), dim3(256), 0, stream, wf, sc, wf + PART);
  hipLaunchKernelGGL(final_kernel, dim3(1), dim3(64), 0, stream, wf + PART, out);
}

// Round 4
// 125.446 us; speedup vs baseline: 7.5719x; 1.3600x over previous
//
#include <hip/hip_runtime.h>
#include <math.h>

typedef __attribute__((ext_vector_type(8))) short bf16x8;
typedef __attribute__((ext_vector_type(4))) float f32x4;
typedef unsigned short ushort_t;

#define GN 8192
#define NGRP 1024
#define DDIM 128
#define LOG2E 1.4426950408889634f
#define LN2 0.6931471805599453f

#if __has_builtin(__builtin_amdgcn_exp2f)
#define EXP2F(x) __builtin_amdgcn_exp2f(x)
#else
#define EXP2F(x) exp2f(x)
#endif
#if __has_builtin(__builtin_amdgcn_logf)
#define LOG2FAST(x) __builtin_amdgcn_logf(x)
#else
#define LOG2FAST(x) log2f(x)
#endif

// float offsets in wf (wf = ws + 4MB bf16 region)
#define ROWST 0                          // [2][8192][4 chunks][2: E, L2]
#define GRPB  (ROWST + 2*GN*4*2)         // [2][1024][4 chunks]  (sum of log2 8x8-block sums)
#define DT    (GRPB + 2*NGRP*4)          // [2][8192]  diag-block row sumexp (rel C)
#define DU8   (DT + 2*GN)                // [2][1024]  diag 8x8 block sumexp (rel C)
#define GSUM  (DU8 + 2*NGRP)             // [2][1024][128] per-group column sums
#define CSUM  (GSUM + 2*NGRP*DDIM)       // [2][128] full column sums
#define PART  (CSUM + 2*DDIM)            // [64] loss partials

__device__ __forceinline__ ushort_t f2bf(float x) {
  unsigned u = __float_as_uint(x);
  unsigned r = (u + 0x7fffu + ((u >> 16) & 1u)) >> 16;
  return (ushort_t)r;
}
__device__ __forceinline__ float bf2f(unsigned h) {
  return __uint_as_float(h << 16);
}

__global__ __launch_bounds__(64) void norm_kernel(
    const float* __restrict__ f1, const float* __restrict__ f2,
    const float* __restrict__ scp, ushort_t* __restrict__ A1,
    ushort_t* __restrict__ A2) {
  const int i = blockIdx.x;
  const int t = threadIdx.x;
  const float scale = scp[0];
  float2 a = ((const float2*)(f1 + (size_t)i * DDIM))[t];
  float2 b = ((const float2*)(f2 + (size_t)i * DDIM))[t];
  float ss1 = a.x * a.x + a.y * a.y;
  float ss2 = b.x * b.x + b.y * b.y;
  #pragma unroll
  for (int d = 1; d < 64; d <<= 1) {
    ss1 += __shfl_xor(ss1, d);
    ss2 += __shfl_xor(ss2, d);
  }
  const float inv1 = (scale * LOG2E) / sqrtf(ss1);   // fold 1/ln2 into A1
  const float inv2 = 1.0f / sqrtf(ss2);
  ushort2 o1, o2;
  o1.x = f2bf(a.x * inv1); o1.y = f2bf(a.y * inv1);
  o2.x = f2bf(b.x * inv2); o2.y = f2bf(b.y * inv2);
  ((ushort2*)(A1 + (size_t)i * DDIM))[t] = o1;
  ((ushort2*)(A2 + (size_t)i * DDIM))[t] = o2;
}

// per-group column sums (8 rows x 128) for each matrix
__global__ __launch_bounds__(64) void gsum_kernel(
    const ushort_t* __restrict__ wsu, float* __restrict__ wf) {
  const int b = blockIdx.x;            // 0..2047: m*1024 + g
  const int m = b >> 10;
  const int g = b & 1023;
  const int t = threadIdx.x;
  const ushort_t* M = wsu + (size_t)m * GN * DDIM + (size_t)g * 8 * DDIM;
  float s0 = 0.f, s1 = 0.f;
  #pragma unroll
  for (int r = 0; r < 8; ++r) {
    ushort2 v = ((const ushort2*)(M + r * DDIM))[t];
    s0 += bf2f(v.x); s1 += bf2f(v.y);
  }
  wf[GSUM + ((size_t)m * NGRP + g) * DDIM + 2 * t]     = s0;
  wf[GSUM + ((size_t)m * NGRP + g) * DDIM + 2 * t + 1] = s1;
}

__global__ __launch_bounds__(128) void csum_kernel(float* __restrict__ wf) {
  const int m = blockIdx.x;
  const int k = threadIdx.x;
  const float* gp = wf + GSUM + (size_t)m * NGRP * DDIM + k;
  float s = 0.f;
  #pragma unroll 8
  for (int g = 0; g < NGRP; ++g) s += gp[(size_t)g * DDIM];
  wf[CSUM + m * DDIM + k] = s;
}

// grid 1024: idx = pass<<9 | rowblk<<2 | chunk. 64 rows x 2048 cols per block.
// SWAPPED mfma: lane (li,q) reg r holds S[row0+16s+li][cbase + q*4 + r].
__global__ __launch_bounds__(256, 4) void gemm_stats(
    const ushort_t* __restrict__ wsu, const float* __restrict__ scp,
    float* __restrict__ wf) {
  const int idx = blockIdx.x;
  const int pass = idx >> 9;
  const int rowblk = (idx >> 2) & 127;
  const int chunk = idx & 3;
  const int t = threadIdx.x;
  const int w = t >> 6;
  const int l = t & 63;
  const int li = l & 15;
  const int q = l >> 4;
  const float C = scp[0];
  const float nC2 = -C * LOG2E;

  const ushort_t* A = pass ? (wsu + (size_t)GN * DDIM) : wsu;
  const ushort_t* B = pass ? wsu : (wsu + (size_t)GN * DDIM);
  const int row0 = rowblk * 64;

  bf16x8 af[4][4];
  #pragma unroll
  for (int s = 0; s < 4; ++s) {
    #pragma unroll
    for (int ks = 0; ks < 4; ++ks) {
      af[s][ks] = *(const bf16x8*)(const void*)(A + (size_t)(row0 + 16 * s + li) * DDIM + ks * 32 + q * 8);
    }
  }

  float esum[4] = {0.f, 0.f, 0.f, 0.f};
  float sbl[4]  = {0.f, 0.f, 0.f, 0.f};
  float sB[4]   = {0.f, 0.f, 0.f, 0.f};

  const ushort_t* Bp = B + ((size_t)((chunk * 128 + w) * 16) + li) * DDIM + q * 8;
  const int idiag = rowblk - chunk * 32;
  const f32x4 cinit = {nC2, nC2, nC2, nC2};

  #pragma unroll 1
  for (int i = 0; i < 32; ++i) {
    const ushort_t* Bi = Bp + (size_t)i * (64 * DDIM);
    bf16x8 bcur[4];
    #pragma unroll
    for (int ks = 0; ks < 4; ++ks)
      bcur[ks] = *(const bf16x8*)(const void*)(Bi + ks * 32);

    f32x4 acc[4];
    #pragma unroll
    for (int s = 0; s < 4; ++s) acc[s] = cinit;
    #pragma unroll
    for (int ks = 0; ks < 4; ++ks) {
      #pragma unroll
      for (int s = 0; s < 4; ++s)
        acc[s] = __builtin_amdgcn_mfma_f32_16x16x32_bf16(bcur[ks], af[s][ks], acc[s], 0, 0, 0);
    }

    const bool dia = (i == idiag);
    #pragma unroll
    for (int s = 0; s < 4; ++s) {
      float e0 = EXP2F(acc[s][0]);
      float e1 = EXP2F(acc[s][1]);
      float e2 = EXP2F(acc[s][2]);
      float e3 = EXP2F(acc[s][3]);
      float tt = (e0 + e1) + (e2 + e3);
      esum[s] += tt;
      float u = tt + __shfl_xor(tt, 16);     // 8-col block row-sum
      sbl[s] += LOG2FAST(u);
      float v = u + __shfl_xor(u, 1);        // 8x8 block sum (over rows)
      v += __shfl_xor(v, 2);
      v += __shfl_xor(v, 4);
      sB[s] += LOG2FAST(v);
      if (dia && s == w) {
        if (((q >> 1) == (li >> 3)) && ((q & 1) == 0))
          wf[DT + (size_t)pass * GN + row0 + 16 * w + li] = u;
        if (l == 0)  wf[DU8 + (size_t)pass * NGRP + rowblk * 8 + 2 * w]     = v;
        if (l == 40) wf[DU8 + (size_t)pass * NGRP + rowblk * 8 + 2 * w + 1] = v;
      }
    }
  }

  #pragma unroll
  for (int s = 0; s < 4; ++s) {
    esum[s] += __shfl_xor(esum[s], 16); esum[s] += __shfl_xor(esum[s], 32);
    sbl[s]  += __shfl_xor(sbl[s], 16);  sbl[s]  += __shfl_xor(sbl[s], 32);
    sB[s]   += __shfl_xor(sB[s], 16);   sB[s]   += __shfl_xor(sB[s], 32);
  }

  __shared__ float redE[4][64], redL[4][64], redB[4][8];
  if (q == 0) {
    #pragma unroll
    for (int s = 0; s < 4; ++s) {
      redE[w][16 * s + li] = esum[s];
      redL[w][16 * s + li] = 0.5f * sbl[s];
    }
  }
  if (l == 0) {
    #pragma unroll
    for (int s = 0; s < 4; ++s) redB[w][2 * s] = 0.5f * sB[s];
  }
  if (l == 8) {
    #pragma unroll
    for (int s = 0; s < 4; ++s) redB[w][2 * s + 1] = 0.5f * sB[s];
  }
  __syncthreads();

  if (t < 64) {
    const float E = redE[0][t] + redE[1][t] + redE[2][t] + redE[3][t];
    const float L = redL[0][t] + redL[1][t] + redL[2][t] + redL[3][t];
    const size_t o = ROWST + (((size_t)pass * GN + row0 + t) * 4 + chunk) * 2;
    wf[o + 0] = E; wf[o + 1] = L;
  }
  if (t < 8) {
    const float s4 = redB[0][t] + redB[1][t] + redB[2][t] + redB[3][t];
    wf[GRPB + ((size_t)pass * NGRP + rowblk * 8 + t) * 4 + chunk] = s4;
  }
}

__global__ __launch_bounds__(256) void loss_kernel(
    const float* __restrict__ wf, const ushort_t* __restrict__ wsu,
    const float* __restrict__ scp, float* __restrict__ partials) {
  const int b = blockIdx.x;          // 0..63
  const int pass = b >> 5;
  const int rbase = (b & 31) * 256;
  const int t = threadIdx.x;
  const int row = rbase + t;
  const int g = row >> 3;
  const float C = scp[0];
  const float eps = 0.1f;

  const size_t ro = ROWST + (((size_t)pass * GN + row) * 4) * 2;
  float E = wf[ro + 0] + wf[ro + 2] + wf[ro + 4] + wf[ro + 6];
  float L = wf[ro + 1] + wf[ro + 3] + wf[ro + 5] + wf[ro + 7];

  // raw row sum and diag-block raw sum via rank-1 dots
  const ushort_t* M = wsu + (size_t)pass * GN * DDIM + (size_t)row * DDIM;
  const float* cs = wf + CSUM + (size_t)(pass ^ 1) * DDIM;
  const float* gs = wf + GSUM + ((size_t)(pass ^ 1) * NGRP + g) * DDIM;
  float r2 = 0.f, p2 = 0.f;
  const uint4* Mv = (const uint4*)(const void*)M;
  #pragma unroll
  for (int c = 0; c < 8; ++c) {
    uint4 vv = Mv[c];
    unsigned uu[4] = {vv.x, vv.y, vv.z, vv.w};
    #pragma unroll
    for (int j = 0; j < 4; ++j) {
      float flo = bf2f(uu[j] & 0xffffu);
      float fhi = bf2f(uu[j] >> 16);
      const int k = c * 8 + j * 2;
      r2 += flo * cs[k];     r2 += fhi * cs[k + 1];
      p2 += flo * gs[k];     p2 += fhi * gs[k + 1];
    }
  }
  const float R = LN2 * r2;
  const float P = LN2 * p2;

  const float Td = wf[DT + (size_t)pass * GN + row];
  const float logE = __logf(E);
  const float row_lse = C + logE;

  // part_slice
  float acc = ((1.f - eps) * (row_lse - P) + (eps / 8192.f) * (row_lse - R)) * (1.f / 8192.f);
  // whole_slice
  const float dl = C + __logf(Td);
  const float l8 = 9.0099363f;       // log(8192 - 8)
  const float mx = fmaxf(dl, l8);
  const float pos_lse = mx + __logf(__expf(dl - mx) + __expf(l8 - mx));
  acc += ((1.f - eps) * (row_lse - pos_lse) + (eps / 1024.f) * (1024.f * logE - LN2 * L)) * (1.f / 8192.f);

  __shared__ float shE[256], shR[256], shP[256];
  shE[t] = E; shR[t] = R; shP[t] = P;
  __syncthreads();
  if (t < 32) {
    float Eg = 0.f, Rg = 0.f, Pg = 0.f;
    #pragma unroll
    for (int j = 0; j < 8; ++j) { Eg += shE[t * 8 + j]; Rg += shR[t * 8 + j]; Pg += shP[t * 8 + j]; }
    const int g2 = (rbase >> 3) + t;
    float SB = 0.f;
    #pragma unroll
    for (int ch = 0; ch < 4; ++ch) SB += wf[GRPB + ((size_t)pass * NGRP + g2) * 4 + ch];
    const float U = wf[DU8 + (size_t)pass * NGRP + g2];
    const float logEg = __logf(Eg);
    const float grp_lse = C + logEg;
    // part_block
    acc += ((1.f - eps) * (grp_lse - Pg * (1.f / 64.f)) + eps * (grp_lse - Rg * (1.f / 65536.f))) * (1.f / 1024.f);
    // whole_block
    const float dbl = C + __logf(U);
    acc += ((1.f - eps) * (grp_lse - dbl) + (eps / 1024.f) * (1024.f * logEg - LN2 * SB)) * (1.f / 1024.f);
  }

  #pragma unroll
  for (int d = 1; d < 64; d <<= 1) acc += __shfl_xor(acc, d);
  __shared__ float sr[4];
  if ((t & 63) == 0) sr[t >> 6] = acc;
  __syncthreads();
  if (t == 0) partials[b] = sr[0] + sr[1] + sr[2] + sr[3];
}

__global__ __launch_bounds__(64) void final_kernel(
    const float* __restrict__ partials, float* __restrict__ out) {
  const int t = threadIdx.x;
  float v = partials[t];
  #pragma unroll
  for (int d = 1; d < 64; d <<= 1) v += __shfl_xor(v, d);
  if (t == 0) out[0] = 0.125f * v;
}

extern "C" void kernel_launch(void* const* d_in, const int* in_sizes, int n_in,
                              void* d_out, int out_size, void* d_ws, size_t ws_size,
                              hipStream_t stream) {
  const float* f1 = (const float*)d_in[0];
  const float* f2 = (const float*)d_in[1];
  const float* sc = (const float*)d_in[2];
  ushort_t* wsu = (ushort_t*)d_ws;
  float* wf = (float*)((char*)d_ws + (size_t)2 * GN * DDIM * sizeof(ushort_t));
  float* out = (float*)d_out;

  hipLaunchKernelGGL(norm_kernel, dim3(GN), dim3(64), 0, stream,
                     f1, f2, sc, wsu, wsu + (size_t)GN * DDIM);
  hipLaunchKernelGGL(gsum_kernel, dim3(2048), dim3(64), 0, stream, wsu, wf);
  hipLaunchKernelGGL(csum_kernel, dim3(2), dim3(128), 0, stream, wf);
  hipLaunchKernelGGL(gemm_stats, dim3(1024), dim3(256), 0, stream, wsu, sc, wf);
  hipLaunchKernelGGL(loss_kernel, dim3(64), dim3(256), 0, stream, wf, wsu, sc, wf + PART);
  hipLaunchKernelGGL(final_kernel, dim3(1), dim3(64), 0, stream, wf + PART, out);
}

// Round 5
// 96.194 us; speedup vs baseline: 9.8745x; 1.3041x over previous
//
#include <hip/hip_runtime.h>
#include <math.h>

typedef __attribute__((ext_vector_type(8))) short bf16x8;
typedef __attribute__((ext_vector_type(4))) float f32x4;
typedef unsigned short ushort_t;

#define GN 8192
#define NGRP 1024
#define DDIM 128
#define LOG2E 1.4426950408889634f
#define LN2 0.6931471805599453f

#if __has_builtin(__builtin_amdgcn_exp2f)
#define EXP2F(x) __builtin_amdgcn_exp2f(x)
#else
#define EXP2F(x) exp2f(x)
#endif
#if __has_builtin(__builtin_amdgcn_logf)
#define LOG2FAST(x) __builtin_amdgcn_logf(x)
#else
#define LOG2FAST(x) log2f(x)
#endif

// float offsets in wf (wf = ws + 4MB bf16 region)
#define ROWST 0                          // [2][8192][8 chunks][2: E, L2]
#define GRPB  (ROWST + 2*GN*8*2)         // [2][1024][8 chunks] (sum of log2 8x8-block sums)
#define DT    (GRPB + 2*NGRP*8)          // [2][8192]  diag-block row sumexp (rel C)
#define DU8   (DT + 2*GN)                // [2][1024]  diag 8x8 block sumexp (rel C)
#define GSUM  (DU8 + 2*NGRP)             // [2][1024][128] per-group column sums
#define CSUMP (GSUM + 2*NGRP*DDIM)       // [2][32][128] column-sum partials
#define PART  (CSUMP + 2*32*DDIM)        // [64] loss partials

__device__ __forceinline__ ushort_t f2bf(float x) {
  unsigned u = __float_as_uint(x);
  unsigned r = (u + 0x7fffu + ((u >> 16) & 1u)) >> 16;
  return (ushort_t)r;
}
__device__ __forceinline__ float bf2f(unsigned h) {
  return __uint_as_float(h << 16);
}

// One block per (matrix m, group g): normalize 8 rows, store bf16, emit
// per-group column sums of the bf16-rounded values.
__global__ __launch_bounds__(256) void normg_kernel(
    const float* __restrict__ f1, const float* __restrict__ f2,
    const float* __restrict__ scp, ushort_t* __restrict__ wsu,
    float* __restrict__ wf) {
  const int b = blockIdx.x;            // m*1024 + g
  const int m = b >> 10;
  const int g = b & 1023;
  const int t = threadIdx.x;
  const int r = t >> 5;                // row in group, 0..7
  const int c4 = t & 31;               // 4-col quarter
  const float* __restrict__ f = m ? f2 : f1;
  const float fac0 = m ? 1.0f : (scp[0] * LOG2E);

  const float4 v = ((const float4*)(f + ((size_t)(g * 8 + r)) * DDIM))[c4];
  float ss = v.x * v.x + v.y * v.y + v.z * v.z + v.w * v.w;
  #pragma unroll
  for (int d = 1; d < 32; d <<= 1) ss += __shfl_xor(ss, d);
  const float inv = fac0 / sqrtf(ss);

  ushort4 o;
  o.x = f2bf(v.x * inv); o.y = f2bf(v.y * inv);
  o.z = f2bf(v.z * inv); o.w = f2bf(v.w * inv);
  ((ushort4*)(wsu + (size_t)m * GN * DDIM + (size_t)(g * 8 + r) * DDIM))[c4] = o;

  __shared__ float lds[8][DDIM];
  lds[r][c4 * 4 + 0] = bf2f(o.x);
  lds[r][c4 * 4 + 1] = bf2f(o.y);
  lds[r][c4 * 4 + 2] = bf2f(o.z);
  lds[r][c4 * 4 + 3] = bf2f(o.w);
  __syncthreads();
  if (t < DDIM) {
    float s = 0.f;
    #pragma unroll
    for (int j = 0; j < 8; ++j) s += lds[j][t];
    wf[GSUM + ((size_t)m * NGRP + g) * DDIM + t] = s;
  }
}

// column-sum partials: block (m, seg) sums 32 groups for each of 128 cols
__global__ __launch_bounds__(128) void csum_kernel(float* __restrict__ wf) {
  const int b = blockIdx.x;            // m*32 + seg
  const int m = b >> 5;
  const int seg = b & 31;
  const int k = threadIdx.x;
  const float* gp = wf + GSUM + ((size_t)m * NGRP + seg * 32) * DDIM + k;
  float s = 0.f;
  #pragma unroll 8
  for (int g = 0; g < 32; ++g) s += gp[(size_t)g * DDIM];
  wf[CSUMP + ((size_t)m * 32 + seg) * DDIM + k] = s;
}

// grid 2048: idx = pass<<10 | chunk<<7 | rowblk. 64 rows x 1024 cols per block.
// SWAPPED mfma: lane (li,q) reg r holds S[row0+16s+li][colbase + q*4 + r].
__global__ __launch_bounds__(256, 4) void gemm_stats(
    const ushort_t* __restrict__ wsu, const float* __restrict__ scp,
    float* __restrict__ wf) {
  const int idx = blockIdx.x;
  const int pass = idx >> 10;
  const int chunk = (idx >> 7) & 7;
  const int rowblk = idx & 127;
  const int t = threadIdx.x;
  const int w = t >> 6;
  const int l = t & 63;
  const int li = l & 15;
  const int q = l >> 4;
  const float C = scp[0];
  const float nC2 = -C * LOG2E;

  const ushort_t* A = pass ? (wsu + (size_t)GN * DDIM) : wsu;
  const ushort_t* B = pass ? wsu : (wsu + (size_t)GN * DDIM);
  const int row0 = rowblk * 64;

  bf16x8 af[4][4];
  #pragma unroll
  for (int s = 0; s < 4; ++s) {
    #pragma unroll
    for (int ks = 0; ks < 4; ++ks) {
      af[s][ks] = *(const bf16x8*)(const void*)(A + (size_t)(row0 + 16 * s + li) * DDIM + ks * 32 + q * 8);
    }
  }

  float esum[4] = {0.f, 0.f, 0.f, 0.f};
  float sbl[4]  = {0.f, 0.f, 0.f, 0.f};
  float sB[4]   = {0.f, 0.f, 0.f, 0.f};

  const ushort_t* Bp = B + ((size_t)((chunk * 64 + w) * 16) + li) * DDIM + q * 8;
  const int idiag = rowblk - chunk * 16;
  const f32x4 cinit = {nC2, nC2, nC2, nC2};

  #pragma unroll 1
  for (int i = 0; i < 16; ++i) {
    const ushort_t* Bi = Bp + (size_t)i * (64 * DDIM);
    bf16x8 bcur[4];
    #pragma unroll
    for (int ks = 0; ks < 4; ++ks)
      bcur[ks] = *(const bf16x8*)(const void*)(Bi + ks * 32);

    f32x4 acc[4];
    #pragma unroll
    for (int s = 0; s < 4; ++s) acc[s] = cinit;
    #pragma unroll
    for (int ks = 0; ks < 4; ++ks) {
      #pragma unroll
      for (int s = 0; s < 4; ++s)
        acc[s] = __builtin_amdgcn_mfma_f32_16x16x32_bf16(bcur[ks], af[s][ks], acc[s], 0, 0, 0);
    }

    const bool dia = (i == idiag);
    #pragma unroll
    for (int s = 0; s < 4; ++s) {
      float e0 = EXP2F(acc[s][0]);
      float e1 = EXP2F(acc[s][1]);
      float e2 = EXP2F(acc[s][2]);
      float e3 = EXP2F(acc[s][3]);
      float tt = (e0 + e1) + (e2 + e3);
      esum[s] += tt;
      float u = tt + __shfl_xor(tt, 16);     // 8-col block row-sum
      sbl[s] += LOG2FAST(u);
      float v = u + __shfl_xor(u, 1);        // 8x8 block sum (over rows)
      v += __shfl_xor(v, 2);
      v += __shfl_xor(v, 4);
      sB[s] += LOG2FAST(v);
      if (dia && s == w) {
        if (((q >> 1) == (li >> 3)) && ((q & 1) == 0))
          wf[DT + (size_t)pass * GN + row0 + 16 * w + li] = u;
        if (l == 0)  wf[DU8 + (size_t)pass * NGRP + rowblk * 8 + 2 * w]     = v;
        if (l == 40) wf[DU8 + (size_t)pass * NGRP + rowblk * 8 + 2 * w + 1] = v;
      }
    }
  }

  #pragma unroll
  for (int s = 0; s < 4; ++s) {
    esum[s] += __shfl_xor(esum[s], 16); esum[s] += __shfl_xor(esum[s], 32);
    sbl[s]  += __shfl_xor(sbl[s], 16);  sbl[s]  += __shfl_xor(sbl[s], 32);
    sB[s]   += __shfl_xor(sB[s], 16);   sB[s]   += __shfl_xor(sB[s], 32);
  }

  __shared__ float redE[4][64], redL[4][64], redB[4][8];
  if (q == 0) {
    #pragma unroll
    for (int s = 0; s < 4; ++s) {
      redE[w][16 * s + li] = esum[s];
      redL[w][16 * s + li] = 0.5f * sbl[s];
    }
  }
  if (l == 0) {
    #pragma unroll
    for (int s = 0; s < 4; ++s) redB[w][2 * s] = 0.5f * sB[s];
  }
  if (l == 8) {
    #pragma unroll
    for (int s = 0; s < 4; ++s) redB[w][2 * s + 1] = 0.5f * sB[s];
  }
  __syncthreads();

  if (t < 64) {
    const float E = redE[0][t] + redE[1][t] + redE[2][t] + redE[3][t];
    const float L = redL[0][t] + redL[1][t] + redL[2][t] + redL[3][t];
    const size_t o = ROWST + (((size_t)pass * GN + row0 + t) * 8 + chunk) * 2;
    wf[o + 0] = E; wf[o + 1] = L;
  }
  if (t < 8) {
    const float s4 = redB[0][t] + redB[1][t] + redB[2][t] + redB[3][t];
    wf[GRPB + ((size_t)pass * NGRP + rowblk * 8 + t) * 8 + chunk] = s4;
  }
}

__global__ __launch_bounds__(256) void loss_kernel(
    const float* __restrict__ wf, const ushort_t* __restrict__ wsu,
    const float* __restrict__ scp, float* __restrict__ partials) {
  const int b = blockIdx.x;          // 0..63
  const int pass = b >> 5;
  const int rbase = (b & 31) * 256;
  const int t = threadIdx.x;
  const int row = rbase + t;
  const int g = row >> 3;
  const float C = scp[0];
  const float eps = 0.1f;

  // fold the 32 column-sum partials of the OTHER matrix into LDS
  __shared__ float cs_l[DDIM];
  if (t < DDIM) {
    const float* cp = wf + CSUMP + ((size_t)(pass ^ 1) * 32) * DDIM + t;
    float s = 0.f;
    #pragma unroll 8
    for (int seg = 0; seg < 32; ++seg) s += cp[(size_t)seg * DDIM];
    cs_l[t] = s;
  }
  __syncthreads();

  const size_t ro = ROWST + (((size_t)pass * GN + row) * 8) * 2;
  float E = 0.f, L = 0.f;
  #pragma unroll
  for (int ch = 0; ch < 8; ++ch) {
    E += wf[ro + 2 * ch];
    L += wf[ro + 2 * ch + 1];
  }

  // raw row sum and diag-block raw sum via rank-1 dots
  const ushort_t* M = wsu + (size_t)pass * GN * DDIM + (size_t)row * DDIM;
  const float* gs = wf + GSUM + ((size_t)(pass ^ 1) * NGRP + g) * DDIM;
  float r2 = 0.f, p2 = 0.f;
  const uint4* Mv = (const uint4*)(const void*)M;
  #pragma unroll
  for (int c = 0; c < 8; ++c) {
    uint4 vv = Mv[c];
    unsigned uu[4] = {vv.x, vv.y, vv.z, vv.w};
    #pragma unroll
    for (int j = 0; j < 4; ++j) {
      float flo = bf2f(uu[j] & 0xffffu);
      float fhi = bf2f(uu[j] >> 16);
      const int k = c * 8 + j * 2;
      r2 += flo * cs_l[k];   r2 += fhi * cs_l[k + 1];
      p2 += flo * gs[k];     p2 += fhi * gs[k + 1];
    }
  }
  const float R = LN2 * r2;
  const float P = LN2 * p2;

  const float Td = wf[DT + (size_t)pass * GN + row];
  const float logE = __logf(E);
  const float row_lse = C + logE;

  // part_slice
  float acc = ((1.f - eps) * (row_lse - P) + (eps / 8192.f) * (row_lse - R)) * (1.f / 8192.f);
  // whole_slice
  const float dl = C + __logf(Td);
  const float l8 = 9.0099363f;       // log(8192 - 8)
  const float mx = fmaxf(dl, l8);
  const float pos_lse = mx + __logf(__expf(dl - mx) + __expf(l8 - mx));
  acc += ((1.f - eps) * (row_lse - pos_lse) + (eps / 1024.f) * (1024.f * logE - LN2 * L)) * (1.f / 8192.f);

  __shared__ float shE[256], shR[256], shP[256];
  shE[t] = E; shR[t] = R; shP[t] = P;
  __syncthreads();
  if (t < 32) {
    float Eg = 0.f, Rg = 0.f, Pg = 0.f;
    #pragma unroll
    for (int j = 0; j < 8; ++j) { Eg += shE[t * 8 + j]; Rg += shR[t * 8 + j]; Pg += shP[t * 8 + j]; }
    const int g2 = (rbase >> 3) + t;
    float SB = 0.f;
    #pragma unroll
    for (int ch = 0; ch < 8; ++ch) SB += wf[GRPB + ((size_t)pass * NGRP + g2) * 8 + ch];
    const float U = wf[DU8 + (size_t)pass * NGRP + g2];
    const float logEg = __logf(Eg);
    const float grp_lse = C + logEg;
    // part_block
    acc += ((1.f - eps) * (grp_lse - Pg * (1.f / 64.f)) + eps * (grp_lse - Rg * (1.f / 65536.f))) * (1.f / 1024.f);
    // whole_block
    const float dbl = C + __logf(U);
    acc += ((1.f - eps) * (grp_lse - dbl) + (eps / 1024.f) * (1024.f * logEg - LN2 * SB)) * (1.f / 1024.f);
  }

  #pragma unroll
  for (int d = 1; d < 64; d <<= 1) acc += __shfl_xor(acc, d);
  __shared__ float sr[4];
  if ((t & 63) == 0) sr[t >> 6] = acc;
  __syncthreads();
  if (t == 0) partials[b] = sr[0] + sr[1] + sr[2] + sr[3];
}

__global__ __launch_bounds__(64) void final_kernel(
    const float* __restrict__ partials, float* __restrict__ out) {
  const int t = threadIdx.x;
  float v = partials[t];
  #pragma unroll
  for (int d = 1; d < 64; d <<= 1) v += __shfl_xor(v, d);
  if (t == 0) out[0] = 0.125f * v;
}

extern "C" void kernel_launch(void* const* d_in, const int* in_sizes, int n_in,
                              void* d_out, int out_size, void* d_ws, size_t ws_size,
                              hipStream_t stream) {
  const float* f1 = (const float*)d_in[0];
  const float* f2 = (const float*)d_in[1];
  const float* sc = (const float*)d_in[2];
  ushort_t* wsu = (ushort_t*)d_ws;
  float* wf = (float*)((char*)d_ws + (size_t)2 * GN * DDIM * sizeof(ushort_t));
  float* out = (float*)d_out;

  hipLaunchKernelGGL(normg_kernel, dim3(2048), dim3(256), 0, stream, f1, f2, sc, wsu, wf);
  hipLaunchKernelGGL(csum_kernel, dim3(64), dim3(128), 0, stream, wf);
  hipLaunchKernelGGL(gemm_stats, dim3(2048), dim3(256), 0, stream, wsu, sc, wf);
  hipLaunchKernelGGL(loss_kernel, dim3(64), dim3(256), 0, stream, wf, wsu, sc, wf + PART);
  hipLaunchKernelGGL(final_kernel, dim3(1), dim3(64), 0, stream, wf + PART, out);
}